// Round 1
// baseline (65.723 us; speedup 1.0000x reference)
//
#include <hip/hip_runtime.h>

#define ROWN 512
constexpr float MARGIN = 1.0f;

// One block per batch row. Compact pos/neg scores into LDS, then each thread
// accumulates hinge over (its positives) x (all negatives).
__global__ __launch_bounds__(256) void pmrl_rows(const float* __restrict__ scores,
                                                 const int* __restrict__ labels,
                                                 float* __restrict__ row_sum,
                                                 unsigned int* __restrict__ row_pairs) {
    __shared__ float pos_s[ROWN];
    __shared__ float neg_s[ROWN];
    __shared__ int cnts[2];   // [0]=pos count, [1]=neg count
    __shared__ float wsum[4];

    const int row = blockIdx.x;
    const int t   = threadIdx.x;

    if (t < 2) cnts[t] = 0;
    __syncthreads();

    const float* s = scores + (size_t)row * ROWN;
    const int*   l = labels + (size_t)row * ROWN;

    for (int i = t; i < ROWN; i += 256) {
        float v   = s[i];
        int   lab = l[i];
        if (lab == 1) {
            int idx = atomicAdd(&cnts[0], 1);
            pos_s[idx] = v;
        } else if (lab == 0) {
            int idx = atomicAdd(&cnts[1], 1);
            neg_s[idx] = v;
        }
    }
    __syncthreads();

    const int P = cnts[0];
    const int Q = cnts[1];

    float acc = 0.0f;
    for (int i = t; i < P; i += 256) {
        const float base = MARGIN - pos_s[i];
        float local = 0.0f;
        for (int j = 0; j < Q; ++j) {
            // neg_s[j] is wave-uniform per iteration -> LDS broadcast, no conflicts
            local += fmaxf(base + neg_s[j], 0.0f);
        }
        acc += local;
    }

    // wave(64) shuffle reduction
    #pragma unroll
    for (int off = 32; off > 0; off >>= 1) acc += __shfl_down(acc, off, 64);
    if ((t & 63) == 0) wsum[t >> 6] = acc;
    __syncthreads();

    if (t == 0) {
        row_sum[row]   = wsum[0] + wsum[1] + wsum[2] + wsum[3];
        row_pairs[row] = (unsigned int)(P * Q);
    }
}

// Single-wave final reduction in double for the ~3e7-magnitude total.
__global__ __launch_bounds__(64) void pmrl_final(const float* __restrict__ row_sum,
                                                 const unsigned int* __restrict__ row_pairs,
                                                 float* __restrict__ out) {
    const int t = threadIdx.x;
    double s = 0.0;
    unsigned long long pc = 0ull;
    for (int i = t; i < ROWN; i += 64) {
        s  += (double)row_sum[i];
        pc += (unsigned long long)row_pairs[i];
    }
    #pragma unroll
    for (int off = 32; off > 0; off >>= 1) {
        s  += __shfl_down(s, off, 64);
        pc += __shfl_down(pc, off, 64);
    }
    if (t == 0) {
        out[0] = (pc > 0ull) ? (float)(s / (double)pc) : 0.0f;
    }
}

extern "C" void kernel_launch(void* const* d_in, const int* in_sizes, int n_in,
                              void* d_out, int out_size, void* d_ws, size_t ws_size,
                              hipStream_t stream) {
    const float* scores = (const float*)d_in[0];
    const int*   labels = (const int*)d_in[1];
    float*       out    = (float*)d_out;

    // workspace layout: 512 f32 row sums, then 512 u32 pair counts
    float*        row_sum   = (float*)d_ws;
    unsigned int* row_pairs = (unsigned int*)((char*)d_ws + ROWN * sizeof(float));

    pmrl_rows<<<ROWN, 256, 0, stream>>>(scores, labels, row_sum, row_pairs);
    pmrl_final<<<1, 64, 0, stream>>>(row_sum, row_pairs, out);
}

// Round 2
// 64.220 us; speedup vs baseline: 1.0234x; 1.0234x over previous
//
#include <hip/hip_runtime.h>

#define ROWN 512
constexpr float MARGIN = 1.0f;
constexpr float NEG_INF = -1e30f;

// One block per batch row. Ballot-based compaction of pos/neg scores into LDS
// (16 LDS atomics/block instead of 512 serialized same-address ones), then
// float4 inner loop over negatives (ds_read_b128 broadcast, no conflicts).
__global__ __launch_bounds__(256) void pmrl_rows(const float* __restrict__ scores,
                                                 const int* __restrict__ labels,
                                                 float* __restrict__ row_sum,
                                                 unsigned int* __restrict__ row_pairs) {
    __shared__ float pos_s[ROWN];
    __shared__ float neg_s[ROWN + 4];   // +4 for -inf padding to multiple of 4
    __shared__ int cnts[2];             // [0]=pos count, [1]=neg count
    __shared__ float wsum[4];

    const int row  = blockIdx.x;
    const int t    = threadIdx.x;
    const int lane = t & 63;

    if (t < 2) cnts[t] = 0;
    __syncthreads();

    const float* s = scores + (size_t)row * ROWN;
    const int*   l = labels + (size_t)row * ROWN;

    #pragma unroll
    for (int r = 0; r < 2; ++r) {
        const int i   = t + r * 256;
        const float v = s[i];
        const int lab = l[i];
        const bool isp = (lab == 1);
        const bool isn = (lab == 0);
        const unsigned long long bp = __ballot(isp);
        const unsigned long long bn = __ballot(isn);
        const unsigned long long ltmask = (1ull << lane) - 1ull;
        const int pp = __popcll(bp & ltmask);
        const int pn = __popcll(bn & ltmask);
        int basep = 0, basen = 0;
        if (lane == 0) {
            basep = atomicAdd(&cnts[0], __popcll(bp));
            basen = atomicAdd(&cnts[1], __popcll(bn));
        }
        basep = __shfl(basep, 0, 64);
        basen = __shfl(basen, 0, 64);
        if (isp) pos_s[basep + pp] = v;
        if (isn) neg_s[basen + pn] = v;
    }
    __syncthreads();

    const int P = cnts[0];
    const int Q = cnts[1];

    // pad negatives to a multiple of 4 with -inf so padded lanes contribute 0
    const int pad = (4 - (Q & 3)) & 3;
    if (t < pad) neg_s[Q + t] = NEG_INF;
    __syncthreads();
    const int Q4 = (Q + 3) >> 2;

    float acc = 0.0f;
    const float4* neg4 = (const float4*)neg_s;
    for (int i = t; i < P; i += 256) {
        const float c = MARGIN - pos_s[i];
        float a0 = 0.f, a1 = 0.f, a2 = 0.f, a3 = 0.f;
        for (int j = 0; j < Q4; ++j) {
            // same address across the wave -> ds_read_b128 broadcast, conflict-free
            const float4 n = neg4[j];
            a0 += fmaxf(c + n.x, 0.0f);
            a1 += fmaxf(c + n.y, 0.0f);
            a2 += fmaxf(c + n.z, 0.0f);
            a3 += fmaxf(c + n.w, 0.0f);
        }
        acc += (a0 + a1) + (a2 + a3);
    }

    // wave(64) shuffle reduction, then 4-wave combine
    #pragma unroll
    for (int off = 32; off > 0; off >>= 1) acc += __shfl_down(acc, off, 64);
    if (lane == 0) wsum[t >> 6] = acc;
    __syncthreads();

    if (t == 0) {
        row_sum[row]   = (wsum[0] + wsum[1]) + (wsum[2] + wsum[3]);
        row_pairs[row] = (unsigned int)(P * Q);
    }
}

// Single-wave final reduction in double for the ~4e7-magnitude total.
__global__ __launch_bounds__(64) void pmrl_final(const float* __restrict__ row_sum,
                                                 const unsigned int* __restrict__ row_pairs,
                                                 float* __restrict__ out) {
    const int t = threadIdx.x;
    double s = 0.0;
    unsigned long long pc = 0ull;
    for (int i = t; i < ROWN; i += 64) {
        s  += (double)row_sum[i];
        pc += (unsigned long long)row_pairs[i];
    }
    #pragma unroll
    for (int off = 32; off > 0; off >>= 1) {
        s  += __shfl_down(s, off, 64);
        pc += __shfl_down(pc, off, 64);
    }
    if (t == 0) {
        out[0] = (pc > 0ull) ? (float)(s / (double)pc) : 0.0f;
    }
}

extern "C" void kernel_launch(void* const* d_in, const int* in_sizes, int n_in,
                              void* d_out, int out_size, void* d_ws, size_t ws_size,
                              hipStream_t stream) {
    const float* scores = (const float*)d_in[0];
    const int*   labels = (const int*)d_in[1];
    float*       out    = (float*)d_out;

    float*        row_sum   = (float*)d_ws;
    unsigned int* row_pairs = (unsigned int*)((char*)d_ws + ROWN * sizeof(float));

    pmrl_rows<<<ROWN, 256, 0, stream>>>(scores, labels, row_sum, row_pairs);
    pmrl_final<<<1, 64, 0, stream>>>(row_sum, row_pairs, out);
}